// Round 9
// baseline (158.907 us; speedup 1.0000x reference)
//
#include <hip/hip_runtime.h>
#include <hip/hip_bf16.h>
#include <math.h>

// Problem constants
constexpr int cHW   = 4096;   // H*W
constexpr int cC    = 128;
constexpr int cNH   = 4;
constexpr int cDH   = 32;
constexpr float cEPS = 1e-5f;
// dh^-0.5 * log2(e): scores in log2 domain, softmax via exp2, fixed max=0
constexpr float cQS = 0.2550347805f;
constexpr int SPLIT = 8;

typedef short bh8 __attribute__((ext_vector_type(8)));   // 8 bf16 (4 VGPRs)
typedef float f4  __attribute__((ext_vector_type(4)));   // MFMA C/D
typedef unsigned u4 __attribute__((ext_vector_type(4)));

static __device__ __forceinline__ unsigned short f2bf(float f) {
  union { __hip_bfloat16 h; unsigned short u; } cv;
  cv.h = __float2bfloat16(f);
  return cv.u;
}
static __device__ __forceinline__ unsigned pack2bf(float a, float b) {
  return (unsigned)f2bf(a) | ((unsigned)f2bf(b) << 16);
}
// truncating pack: 2 VALU. Error cancels in softmax since l is computed
// from the same truncated P via MFMA-with-ones.
static __device__ __forceinline__ unsigned pack_trunc(float a, float b) {
  unsigned ua = __builtin_bit_cast(unsigned, a);
  unsigned ub = __builtin_bit_cast(unsigned, b);
  return (ua >> 16) | (ub & 0xffff0000u);
}
static __device__ __forceinline__ float bflo(unsigned pk) {
  return __builtin_bit_cast(float, pk << 16);
}
static __device__ __forceinline__ float bfhi(unsigned pk) {
  return __builtin_bit_cast(float, pk & 0xffff0000u);
}

// ---------------- block reduce (sum of two values over 256 threads) -------
__device__ __forceinline__ void block_reduce2(float& a, float& b, float* sbuf) {
  #pragma unroll
  for (int off = 32; off > 0; off >>= 1) {
    a += __shfl_down(a, off, 64);
    b += __shfl_down(b, off, 64);
  }
  int wave = threadIdx.x >> 6;
  int lane = threadIdx.x & 63;
  if (lane == 0) { sbuf[wave] = a; sbuf[4 + wave] = b; }
  __syncthreads();
  if (threadIdx.x == 0) {
    sbuf[8] = sbuf[0] + sbuf[1] + sbuf[2] + sbuf[3];
    sbuf[9] = sbuf[4] + sbuf[5] + sbuf[6] + sbuf[7];
  }
  __syncthreads();
  a = sbuf[8];
  b = sbuf[9];
}

// ---------------- prep: GN1 stats partials + weight transpose/pack --------
// blocks 0..255: stats of x; blocks 256..271: pack w_qkv / w_out to [d][c] bf16
__global__ __launch_bounds__(256)
void prep(const float* __restrict__ x, float* __restrict__ part,
          const float* __restrict__ wq, const float* __restrict__ wo,
          unsigned short* __restrict__ wqT, unsigned short* __restrict__ woT) {
  __shared__ float lds[32 * 133];
  int L = threadIdx.x;
  if (blockIdx.x < 256) {
    int ng = blockIdx.x >> 3, sl = blockIdx.x & 7;
    const float4* s4 = (const float4*)x;
    float s = 0.f, s2 = 0.f;
    #pragma unroll
    for (int i = 0; i < 4; i++) {
      int idx = i * 256 + L;
      int c = idx >> 7, tt = idx & 127;
      float4 v = s4[(size_t)(ng * 8 + c) * 1024 + sl * 128 + tt];
      s  += v.x + v.y + v.z + v.w;
      s2 += v.x*v.x + v.y*v.y + v.z*v.z + v.w*v.w;
    }
    block_reduce2(s, s2, lds);
    if (L == 0) { part[blockIdx.x * 2] = s; part[blockIdx.x * 2 + 1] = s2; }
  } else {
    int bx = blockIdx.x - 256;
    const float* src; unsigned short* dst; int W, d0;
    if (bx < 12) { src = wq; dst = wqT; W = 384; d0 = bx * 32; }
    else         { src = wo; dst = woT; W = 128; d0 = (bx - 12) * 32; }
    #pragma unroll
    for (int i = 0; i < 16; i++) {
      int c = i * 8 + (L >> 5), d = L & 31;
      lds[d * 133 + c] = src[(size_t)c * W + d0 + d];
    }
    __syncthreads();
    int d = L >> 3, ch = L & 7, c0 = ch * 16;
    unsigned pk[8];
    #pragma unroll
    for (int j = 0; j < 8; j++)
      pk[j] = pack2bf(lds[d * 133 + c0 + 2 * j], lds[d * 133 + c0 + 2 * j + 1]);
    uint4* d4 = (uint4*)(dst + (size_t)(d0 + d) * 128 + c0);
    d4[0] = make_uint4(pk[0], pk[1], pk[2], pk[3]);
    d4[1] = make_uint4(pk[4], pk[5], pk[6], pk[7]);
  }
}

// ---------------- GN stats partials (standalone, for proj) ----------------
__global__ __launch_bounds__(256)
void gn_stats(const float* __restrict__ src, float* __restrict__ part) {
  __shared__ float sbuf[10];
  int ng = blockIdx.x >> 3, sl = blockIdx.x & 7;
  const float4* s4 = (const float4*)src;
  float s = 0.f, s2 = 0.f;
  #pragma unroll
  for (int i = 0; i < 4; i++) {
    int idx = i * 256 + threadIdx.x;
    int c = idx >> 7, tt = idx & 127;
    float4 v = s4[(size_t)(ng * 8 + c) * 1024 + sl * 128 + tt];
    s  += v.x + v.y + v.z + v.w;
    s2 += v.x*v.x + v.y*v.y + v.z*v.z + v.w*v.w;
  }
  block_reduce2(s, s2, sbuf);
  if (threadIdx.x == 0) { part[blockIdx.x * 2] = s; part[blockIdx.x * 2 + 1] = s2; }
}

// ---------------- GN1 apply + bf16 chunk pack -----------------------------
// xnB layout: [n][16 cc][4096 t][8 c] bf16
__global__ __launch_bounds__(256)
void gn1_pack(const float* __restrict__ x, const float* __restrict__ part,
              const float* __restrict__ sc, const float* __restrict__ of,
              unsigned short* __restrict__ xnB) {
  int cc = blockIdx.x, ts = blockIdx.y, n = blockIdx.z;
  int ng = n * 16 + cc;
  float s = 0.f, s2 = 0.f;
  #pragma unroll
  for (int p = 0; p < 8; p++) { s += part[(ng*8+p)*2]; s2 += part[(ng*8+p)*2+1]; }
  float mu = s * (1.0f / 32768.0f);
  float rinv = rsqrtf(s2 * (1.0f / 32768.0f) - mu * mu + cEPS);
  int t = ts * 256 + threadIdx.x;
  float v[8];
  #pragma unroll
  for (int j = 0; j < 8; j++) {
    int c = cc * 8 + j;
    float a = rinv * sc[c];
    float bo = of[c] - mu * a;
    v[j] = x[((size_t)n * cC + c) * cHW + t] * a + bo;
  }
  unsigned pk[4];
  #pragma unroll
  for (int j = 0; j < 4; j++) pk[j] = pack2bf(v[2*j], v[2*j+1]);
  ((uint4*)xnB)[(size_t)(n * 16 + cc) * cHW + t] = make_uint4(pk[0], pk[1], pk[2], pk[3]);
}

// ---------------- QKV projection (MFMA) — R3-proven form ------------------
// grid (64 tt, 12 dg, 2 n), block 256 (4 waves x 16 t-rows)
// vI key ordering within each 32-key block is the PV B-frag permutation:
// virtual pos p = 8Q+j  ->  actual key = (j<4) ? 4Q+j : 16+4Q+(j-4)
__global__ __launch_bounds__(256)
void qkv_mfma(const unsigned short* __restrict__ xnB, const unsigned short* __restrict__ wqT,
              const float* __restrict__ bq, unsigned* __restrict__ qB,
              unsigned* __restrict__ kB, unsigned* __restrict__ vI) {
  __shared__ float vbuf[64 * 36];
  const int L = threadIdx.x & 63, w = threadIdx.x >> 6;
  const int c16 = L & 15, q = L >> 4;
  const int t0 = blockIdx.x * 64, dg = blockIdx.y, n = blockIdx.z;
  const int nh = n * 4 + (dg & 3), d0 = dg * 32;
  const f4 zf = {0.f, 0.f, 0.f, 0.f};
  f4 acc0 = zf, acc1 = zf;
  const int trow = t0 + w * 16 + c16;
  #pragma unroll
  for (int ks = 0; ks < 4; ks++) {
    bh8 a  = *(const bh8*)(xnB + ((size_t)(n * 16 + ks * 4 + q) * cHW + trow) * 8);
    bh8 b0 = *(const bh8*)(wqT + (size_t)(d0 + c16) * 128 + ks * 32 + q * 8);
    bh8 b1 = *(const bh8*)(wqT + (size_t)(d0 + 16 + c16) * 128 + ks * 32 + q * 8);
    acc0 = __builtin_amdgcn_mfma_f32_16x16x32_bf16(a, b0, acc0, 0, 0, 0);
    acc1 = __builtin_amdgcn_mfma_f32_16x16x32_bf16(a, b1, acc1, 0, 0, 0);
  }
  float blo = bq[d0 + c16], bhi = bq[d0 + 16 + c16];
  if (dg < 8) {
    float scl = (dg < 4) ? cQS : 1.0f;
    unsigned* dst = (dg < 4) ? qB : kB;
    #pragma unroll
    for (int r = 0; r < 4; r++) {
      unsigned pk = pack2bf((acc0[r] + blo) * scl, (acc1[r] + bhi) * scl);
      dst[((size_t)nh * cHW + t0 + w * 16 + q * 4 + r) * 16 + c16] = pk;
    }
  } else {
    #pragma unroll
    for (int r = 0; r < 4; r++) {
      vbuf[(w * 16 + q * 4 + r) * 36 + c16]      = acc0[r] + blo;
      vbuf[(w * 16 + q * 4 + r) * 36 + 16 + c16] = acc1[r] + bhi;
    }
    __syncthreads();
    // dword d in 32-key block: Q=d>>2, s=d&3;
    // keys (bk, bk+1) with bk = (s<2) ? 4Q+2s : 16+4Q+2(s-2)
    int d = threadIdx.x & 15, dh8 = (threadIdx.x >> 4) & 15;
    int Q = d >> 2, sd = d & 3;
    int bk = (sd < 2) ? (4 * Q + 2 * sd) : (16 + 4 * Q + 2 * (sd - 2));
    #pragma unroll
    for (int blk = 0; blk < 2; blk++)
      #pragma unroll
      for (int hh = 0; hh < 2; hh++) {
        int dh = dh8 + hh * 16;
        float lo = vbuf[(blk * 32 + bk) * 36 + dh];
        float hi = vbuf[(blk * 32 + bk + 1) * 36 + dh];
        vI[((size_t)nh * 32 + dh) * 2048 + (size_t)(t0 / 32 + blk) * 16 + d] = pack2bf(lo, hi);
      }
  }
}

// ---------------- MFMA flash attention, operand-swapped, no LDS -----------
// Computes S^T = mfma(A=K, B=Q), exp2 in-register, packs P^T lane-locally
// into the PV B-operand (vI pre-permuted), O^T = mfma(A=V^T, B=P^T).
// block = 256 (4 independent waves). grid (32 qb, 8 nh, SPLIT=8).
__global__ __launch_bounds__(256)
void flash_mfma(const unsigned short* __restrict__ qB,
                const unsigned short* __restrict__ kB,
                const unsigned short* __restrict__ vI,
                unsigned* __restrict__ opart, float* __restrict__ lpart) {
  const int w = threadIdx.x >> 6, L = threadIdx.x & 63;
  const int c16 = L & 15, q = L >> 4;   // q = quad
  const int qt = blockIdx.x * 4 + w, nh = blockIdx.y, ph = blockIdx.z;
  const f4 zf = {0.f, 0.f, 0.f, 0.f};
  const short oneb = 0x3F80;        // bf16 1.0
  const bh8 ones = {oneb, oneb, oneb, oneb, oneb, oneb, oneb, oneb};

  // Q as B-operand: B[n=q-row=c16][k=dh-pos=q*8+j]; two q-tiles
  const unsigned short* qb = qB + ((size_t)nh * cHW + qt * 32) * cDH;
  bh8 qfr[2];
  qfr[0] = *(const bh8*)(qb + (size_t)c16 * cDH + q * 8);
  qfr[1] = *(const bh8*)(qb + (size_t)(16 + c16) * cDH + q * 8);

  f4 o[2][2]    = {{zf, zf}, {zf, zf}};  // [dh-tile][q-tile], O^T C-layout
  f4 lacc[2]    = {zf, zf};              // [q-tile]

  const unsigned short* kb = kB + (size_t)nh * cHW * cDH;
  const unsigned short* vb = vI + (size_t)nh * cDH * cHW;

  const int kbeg = ph * (cHW / SPLIT);
  const int kend = kbeg + cHW / SPLIT;

  for (int kt = kbeg; kt < kend; kt += 32) {
    // K as A-operand: A[m=key=c16][k=dh-pos=q*8+j], 2 key-tiles
    bh8 kf0 = *(const bh8*)(kb + (size_t)(kt + c16) * cDH + q * 8);
    bh8 kf1 = *(const bh8*)(kb + (size_t)(kt + 16 + c16) * cDH + q * 8);
    // V^T as A-operand: A[m=dh=c16(+16)][k=virtual key=q*8+j] (pre-permuted)
    bh8 vf0 = *(const bh8*)(vb + (size_t)c16 * cHW + kt + q * 8);
    bh8 vf1 = *(const bh8*)(vb + (size_t)(16 + c16) * cHW + kt + q * 8);

    // S^T tiles [key-tile][q-tile]: lane holds keys kt2*16+4q+r at col c16
    f4 st[2][2];
    st[0][0] = __builtin_amdgcn_mfma_f32_16x16x32_bf16(kf0, qfr[0], zf, 0, 0, 0);
    st[0][1] = __builtin_amdgcn_mfma_f32_16x16x32_bf16(kf0, qfr[1], zf, 0, 0, 0);
    st[1][0] = __builtin_amdgcn_mfma_f32_16x16x32_bf16(kf1, qfr[0], zf, 0, 0, 0);
    st[1][1] = __builtin_amdgcn_mfma_f32_16x16x32_bf16(kf1, qfr[1], zf, 0, 0, 0);

    // exp2 (fixed max 0) — all in-register
    #pragma unroll
    for (int kt2 = 0; kt2 < 2; kt2++)
      #pragma unroll
      for (int qt2 = 0; qt2 < 2; qt2++)
        #pragma unroll
        for (int r = 0; r < 4; r++)
          st[kt2][qt2][r] = __builtin_amdgcn_exp2f(st[kt2][qt2][r]);

    // lane-local pack into P^T B-frags; P x V and P x ones on MFMA pipe
    #pragma unroll
    for (int qt2 = 0; qt2 < 2; qt2++) {
      u4 pu;
      pu.x = pack_trunc(st[0][qt2][0], st[0][qt2][1]);
      pu.y = pack_trunc(st[0][qt2][2], st[0][qt2][3]);
      pu.z = pack_trunc(st[1][qt2][0], st[1][qt2][1]);
      pu.w = pack_trunc(st[1][qt2][2], st[1][qt2][3]);
      bh8 pfr = __builtin_bit_cast(bh8, pu);
      o[0][qt2] = __builtin_amdgcn_mfma_f32_16x16x32_bf16(vf0, pfr, o[0][qt2], 0, 0, 0);
      o[1][qt2] = __builtin_amdgcn_mfma_f32_16x16x32_bf16(vf1, pfr, o[1][qt2], 0, 0, 0);
      lacc[qt2] = __builtin_amdgcn_mfma_f32_16x16x32_bf16(ones, pfr, lacc[qt2], 0, 0, 0);
    }
  }

  // epilogue: O^T[m=dh=q*4+r (+16 for dt1)][n=q-row=c16]
  // opart dword index q*4+r = pair (dh, dh+16) -> one uint4 store per q-tile
  size_t base_r = (size_t)ph * 32768 + (size_t)nh * cHW + (size_t)qt * 32;
  #pragma unroll
  for (int qt2 = 0; qt2 < 2; qt2++) {
    size_t rr = base_r + qt2 * 16 + c16;
    if (q == 0) lpart[rr] = lacc[qt2][0];   // all rows identical (ones-A)
    u4 pk;
    pk.x = pack_trunc(o[0][qt2][0], o[1][qt2][0]);
    pk.y = pack_trunc(o[0][qt2][1], o[1][qt2][1]);
    pk.z = pack_trunc(o[0][qt2][2], o[1][qt2][2]);
    pk.w = pack_trunc(o[0][qt2][3], o[1][qt2][3]);
    *(u4*)(opart + rr * 16 + q * 4) = pk;
  }
}

// ---------------- split-K combine -> yB bf16 [row][32] --------------------
// grid 128, block 256; one thread per row
__global__ __launch_bounds__(256)
void combine(const unsigned* __restrict__ opart, const float* __restrict__ lpart,
             unsigned* __restrict__ yB) {
  size_t r = (size_t)blockIdx.x * 256 + threadIdx.x;
  float l = 0.f;
  #pragma unroll
  for (int p = 0; p < SPLIT; p++) l += lpart[(size_t)p * 32768 + r];
  float e[32];
  #pragma unroll
  for (int j = 0; j < 32; j++) e[j] = 0.f;
  #pragma unroll
  for (int p = 0; p < SPLIT; p++) {
    const uint4* op = (const uint4*)(opart + ((size_t)p * 32768 + r) * 16);
    #pragma unroll
    for (int j = 0; j < 4; j++) {
      uint4 v = op[j];
      e[j*4+0] += bflo(v.x); e[16+j*4+0] += bfhi(v.x);
      e[j*4+1] += bflo(v.y); e[16+j*4+1] += bfhi(v.y);
      e[j*4+2] += bflo(v.z); e[16+j*4+2] += bfhi(v.z);
      e[j*4+3] += bflo(v.w); e[16+j*4+3] += bfhi(v.w);
    }
  }
  float inv = 1.0f / l;
  unsigned pk[16];
  #pragma unroll
  for (int m = 0; m < 16; m++) pk[m] = pack2bf(e[2*m] * inv, e[2*m+1] * inv);
  uint4* dst = (uint4*)(yB + r * 16);
  #pragma unroll
  for (int j = 0; j < 4; j++)
    dst[j] = make_uint4(pk[4*j], pk[4*j+1], pk[4*j+2], pk[4*j+3]);
}

// ---------------- out projection (MFMA) -> proj fp32 [n][c][t] ------------
// grid (64 tt, 4 dg, 2 n), block 256 — R3/R5-proven form (no atomics!)
__global__ __launch_bounds__(256)
void out_mfma(const unsigned short* __restrict__ yB, const unsigned short* __restrict__ woT,
              const float* __restrict__ bo, float* __restrict__ proj) {
  __shared__ float obuf[64 * 36];
  const int L = threadIdx.x & 63, w = threadIdx.x >> 6;
  const int c16 = L & 15, q = L >> 4;
  const int t0 = blockIdx.x * 64, d0 = blockIdx.y * 32, n = blockIdx.z;
  const f4 zf = {0.f, 0.f, 0.f, 0.f};
  f4 acc0 = zf, acc1 = zf;
  const int trow = t0 + w * 16 + c16;
  #pragma unroll
  for (int h = 0; h < 4; h++) {
    bh8 a  = *(const bh8*)(yB + ((size_t)(n * 4 + h) * cHW + trow) * 32 + q * 8);
    bh8 b0 = *(const bh8*)(woT + (size_t)(d0 + c16) * 128 + h * 32 + q * 8);
    bh8 b1 = *(const bh8*)(woT + (size_t)(d0 + 16 + c16) * 128 + h * 32 + q * 8);
    acc0 = __builtin_amdgcn_mfma_f32_16x16x32_bf16(a, b0, acc0, 0, 0, 0);
    acc1 = __builtin_amdgcn_mfma_f32_16x16x32_bf16(a, b1, acc1, 0, 0, 0);
  }
  float blo = bo[d0 + c16], bhi = bo[d0 + 16 + c16];
  #pragma unroll
  for (int r = 0; r < 4; r++) {
    obuf[(w * 16 + q * 4 + r) * 36 + c16]      = acc0[r] + blo;
    obuf[(w * 16 + q * 4 + r) * 36 + 16 + c16] = acc1[r] + bhi;
  }
  __syncthreads();
  int t16 = threadIdx.x & 15, d8 = (threadIdx.x >> 4) & 15;
  #pragma unroll
  for (int tc = 0; tc < 4; tc++)
    #pragma unroll
    for (int hh = 0; hh < 2; hh++) {
      int d = d8 + hh * 16;
      proj[((size_t)n * cC + d0 + d) * cHW + t0 + tc * 16 + t16] =
          obuf[(tc * 16 + t16) * 36 + d];
    }
}

// ---------------- GN2 apply + residual (recomputes xn from x) -------------
__global__ __launch_bounds__(256)
void gn2_apply(const float* __restrict__ x, const float* __restrict__ proj,
               const float* __restrict__ p1, const float* __restrict__ p2,
               const float* __restrict__ s1, const float* __restrict__ o1,
               const float* __restrict__ s2, const float* __restrict__ o2,
               float* __restrict__ out) {
  int tid = blockIdx.x * 256 + threadIdx.x;
  int Cg = tid >> 8;
  int n = Cg >> 7, ch = Cg & 127, g = ch >> 3, ng = n * 16 + g;
  float sa = 0.f, sb = 0.f, ta = 0.f, tb = 0.f;
  #pragma unroll
  for (int p = 0; p < 8; p++) {
    sa += p1[(ng*8+p)*2]; sb += p1[(ng*8+p)*2+1];
    ta += p2[(ng*8+p)*2]; tb += p2[(ng*8+p)*2+1];
  }
  float mu1 = sa * (1.0f/32768.0f);
  float ri1 = rsqrtf(sb * (1.0f/32768.0f) - mu1*mu1 + cEPS);
  float a1 = ri1 * s1[ch], b1 = o1[ch] - mu1 * a1;
  float mu2 = ta * (1.0f/32768.0f);
  float ri2 = rsqrtf(tb * (1.0f/32768.0f) - mu2*mu2 + cEPS);
  float a2 = ri2 * s2[ch], b2 = o2[ch] - mu2 * a2;
  const float4* x4 = (const float4*)x;
  const float4* pr4 = (const float4*)proj;
  float4* o4 = (float4*)out;
  #pragma unroll
  for (int i = 0; i < 4; i++) {
    size_t f = (size_t)tid * 4 + i;
    float4 xv = x4[f], pv = pr4[f];
    float4 r;
    r.x = xv.x * a1 + b1 + pv.x * a2 + b2;
    r.y = xv.y * a1 + b1 + pv.y * a2 + b2;
    r.z = xv.z * a1 + b1 + pv.z * a2 + b2;
    r.w = xv.w * a1 + b1 + pv.w * a2 + b2;
    o4[f] = r;
  }
}

// ---------------- launcher ------------------------------------------------
// Workspace: 25.0 MB total via lifetime aliasing (region B holds xnB+wqT
// early [dead after qkv], opart mid [dead after combine], proj late).
extern "C" void kernel_launch(void* const* d_in, const int* in_sizes, int n_in,
                              void* d_out, int out_size, void* d_ws, size_t ws_size,
                              hipStream_t stream) {
  const float* x     = (const float*)d_in[0];
  const float* w_qkv = (const float*)d_in[1];
  const float* b_qkv = (const float*)d_in[2];
  const float* w_out = (const float*)d_in[3];
  const float* b_out = (const float*)d_in[4];
  const float* g1s   = (const float*)d_in[5];
  const float* g1o   = (const float*)d_in[6];
  const float* g2s   = (const float*)d_in[7];
  const float* g2o   = (const float*)d_in[8];
  float* out = (float*)d_out;

  // ---- Region A (persistent within launch) ----
  unsigned* qB = (unsigned*)d_ws;                         // 524288 u32 (2 MB)
  unsigned* kB = qB + 524288;                             // 2 MB
  unsigned* vI = kB + 524288;                             // 2 MB
  unsigned* yB = vI + 524288;                             // 2 MB
  unsigned short* woT = (unsigned short*)(yB + 524288);   // 16384 ush (32 KB)
  float* stats1 = (float*)(woT + 16384);                  // 512 fl
  float* stats2 = stats1 + 512;                           // 512 fl
  float* lpart  = stats2 + 512;                           // SPLIT*32768 fl (1 MB)
  // ---- Region B (16 MB, time-multiplexed) ----
  unsigned* opart = (unsigned*)(lpart + (size_t)SPLIT * 32768);  // 16 MB
  float* proj = (float*)opart;                            // alias (first 4 MB)
  unsigned short* xnB = (unsigned short*)opart;           // alias (first 2 MB)
  unsigned short* wqT = xnB + 1048576;                    // alias (next 96 KB)

  prep      <<<dim3(272),           256, 0, stream>>>(x, stats1, w_qkv, w_out, wqT, woT);
  gn1_pack  <<<dim3(16, 16, 2),     256, 0, stream>>>(x, stats1, g1s, g1o, xnB);
  qkv_mfma  <<<dim3(64, 12, 2),     256, 0, stream>>>(xnB, wqT, b_qkv, qB, kB, vI);
  flash_mfma<<<dim3(32, 8, SPLIT),  256, 0, stream>>>((const unsigned short*)qB,
                                                      (const unsigned short*)kB,
                                                      (const unsigned short*)vI,
                                                      opart, lpart);
  combine   <<<dim3(128),           256, 0, stream>>>(opart, lpart, yB);
  out_mfma  <<<dim3(64, 4, 2),      256, 0, stream>>>((const unsigned short*)yB, woT,
                                                      b_out, proj);
  gn_stats  <<<dim3(256),           256, 0, stream>>>(proj, stats2);
  gn2_apply <<<dim3(256),           256, 0, stream>>>(x, proj, stats1, stats2,
                                                      g1s, g1o, g2s, g2o, out);
}

// Round 10
// 153.989 us; speedup vs baseline: 1.0319x; 1.0319x over previous
//
#include <hip/hip_runtime.h>
#include <hip/hip_bf16.h>
#include <math.h>

// Problem constants
constexpr int cHW   = 4096;   // H*W
constexpr int cC    = 128;
constexpr int cNH   = 4;
constexpr int cDH   = 32;
constexpr float cEPS = 1e-5f;
// dh^-0.5 * log2(e): scores in log2 domain, softmax via exp2, fixed max=0
constexpr float cQS = 0.2550347805f;
constexpr int SPLIT = 8;

typedef short bh8 __attribute__((ext_vector_type(8)));   // 8 bf16 (4 VGPRs)
typedef float f4  __attribute__((ext_vector_type(4)));   // MFMA C/D
typedef unsigned u4 __attribute__((ext_vector_type(4)));

static __device__ __forceinline__ unsigned short f2bf(float f) {
  union { __hip_bfloat16 h; unsigned short u; } cv;
  cv.h = __float2bfloat16(f);
  return cv.u;
}
static __device__ __forceinline__ unsigned pack2bf(float a, float b) {
  return (unsigned)f2bf(a) | ((unsigned)f2bf(b) << 16);
}
// truncating pack: 2 VALU. Error cancels in softmax since l is computed
// from the same truncated P via MFMA-with-ones.
static __device__ __forceinline__ unsigned pack_trunc(float a, float b) {
  unsigned ua = __builtin_bit_cast(unsigned, a);
  unsigned ub = __builtin_bit_cast(unsigned, b);
  return (ua >> 16) | (ub & 0xffff0000u);
}
static __device__ __forceinline__ float bflo(unsigned pk) {
  return __builtin_bit_cast(float, pk << 16);
}
static __device__ __forceinline__ float bfhi(unsigned pk) {
  return __builtin_bit_cast(float, pk & 0xffff0000u);
}

// ---------------- block reduce (sum of two values over 256 threads) -------
__device__ __forceinline__ void block_reduce2(float& a, float& b, float* sbuf) {
  #pragma unroll
  for (int off = 32; off > 0; off >>= 1) {
    a += __shfl_down(a, off, 64);
    b += __shfl_down(b, off, 64);
  }
  int wave = threadIdx.x >> 6;
  int lane = threadIdx.x & 63;
  if (lane == 0) { sbuf[wave] = a; sbuf[4 + wave] = b; }
  __syncthreads();
  if (threadIdx.x == 0) {
    sbuf[8] = sbuf[0] + sbuf[1] + sbuf[2] + sbuf[3];
    sbuf[9] = sbuf[4] + sbuf[5] + sbuf[6] + sbuf[7];
  }
  __syncthreads();
  a = sbuf[8];
  b = sbuf[9];
}

// ---------------- prep: GN1 stats partials + weight transpose/pack --------
// blocks 0..255: stats of x; blocks 256..271: pack w_qkv / w_out to [d][c] bf16
__global__ __launch_bounds__(256)
void prep(const float* __restrict__ x, float* __restrict__ part,
          const float* __restrict__ wq, const float* __restrict__ wo,
          unsigned short* __restrict__ wqT, unsigned short* __restrict__ woT) {
  __shared__ float lds[32 * 133];
  int L = threadIdx.x;
  if (blockIdx.x < 256) {
    int ng = blockIdx.x >> 3, sl = blockIdx.x & 7;
    const float4* s4 = (const float4*)x;
    float s = 0.f, s2 = 0.f;
    #pragma unroll
    for (int i = 0; i < 4; i++) {
      int idx = i * 256 + L;
      int c = idx >> 7, tt = idx & 127;
      float4 v = s4[(size_t)(ng * 8 + c) * 1024 + sl * 128 + tt];
      s  += v.x + v.y + v.z + v.w;
      s2 += v.x*v.x + v.y*v.y + v.z*v.z + v.w*v.w;
    }
    block_reduce2(s, s2, lds);
    if (L == 0) { part[blockIdx.x * 2] = s; part[blockIdx.x * 2 + 1] = s2; }
  } else {
    int bx = blockIdx.x - 256;
    const float* src; unsigned short* dst; int W, d0;
    if (bx < 12) { src = wq; dst = wqT; W = 384; d0 = bx * 32; }
    else         { src = wo; dst = woT; W = 128; d0 = (bx - 12) * 32; }
    #pragma unroll
    for (int i = 0; i < 16; i++) {
      int c = i * 8 + (L >> 5), d = L & 31;
      lds[d * 133 + c] = src[(size_t)c * W + d0 + d];
    }
    __syncthreads();
    int d = L >> 3, ch = L & 7, c0 = ch * 16;
    unsigned pk[8];
    #pragma unroll
    for (int j = 0; j < 8; j++)
      pk[j] = pack2bf(lds[d * 133 + c0 + 2 * j], lds[d * 133 + c0 + 2 * j + 1]);
    uint4* d4 = (uint4*)(dst + (size_t)(d0 + d) * 128 + c0);
    d4[0] = make_uint4(pk[0], pk[1], pk[2], pk[3]);
    d4[1] = make_uint4(pk[4], pk[5], pk[6], pk[7]);
  }
}

// ---------------- GN1 apply + bf16 chunk pack -----------------------------
// xnB layout: [n][16 cc][4096 t][8 c] bf16
__global__ __launch_bounds__(256)
void gn1_pack(const float* __restrict__ x, const float* __restrict__ part,
              const float* __restrict__ sc, const float* __restrict__ of,
              unsigned short* __restrict__ xnB) {
  int cc = blockIdx.x, ts = blockIdx.y, n = blockIdx.z;
  int ng = n * 16 + cc;
  float s = 0.f, s2 = 0.f;
  #pragma unroll
  for (int p = 0; p < 8; p++) { s += part[(ng*8+p)*2]; s2 += part[(ng*8+p)*2+1]; }
  float mu = s * (1.0f / 32768.0f);
  float rinv = rsqrtf(s2 * (1.0f / 32768.0f) - mu * mu + cEPS);
  int t = ts * 256 + threadIdx.x;
  float v[8];
  #pragma unroll
  for (int j = 0; j < 8; j++) {
    int c = cc * 8 + j;
    float a = rinv * sc[c];
    float bo = of[c] - mu * a;
    v[j] = x[((size_t)n * cC + c) * cHW + t] * a + bo;
  }
  unsigned pk[4];
  #pragma unroll
  for (int j = 0; j < 4; j++) pk[j] = pack2bf(v[2*j], v[2*j+1]);
  ((uint4*)xnB)[(size_t)(n * 16 + cc) * cHW + t] = make_uint4(pk[0], pk[1], pk[2], pk[3]);
}

// ---------------- QKV projection (MFMA) — R3-proven form ------------------
// grid (64 tt, 12 dg, 2 n), block 256 (4 waves x 16 t-rows)
// vI key ordering within each 32-key block is the PV B-frag permutation:
// virtual pos p = 8Q+j  ->  actual key = (j<4) ? 4Q+j : 16+4Q+(j-4)
__global__ __launch_bounds__(256)
void qkv_mfma(const unsigned short* __restrict__ xnB, const unsigned short* __restrict__ wqT,
              const float* __restrict__ bq, unsigned* __restrict__ qB,
              unsigned* __restrict__ kB, unsigned* __restrict__ vI) {
  __shared__ float vbuf[64 * 36];
  const int L = threadIdx.x & 63, w = threadIdx.x >> 6;
  const int c16 = L & 15, q = L >> 4;
  const int t0 = blockIdx.x * 64, dg = blockIdx.y, n = blockIdx.z;
  const int nh = n * 4 + (dg & 3), d0 = dg * 32;
  const f4 zf = {0.f, 0.f, 0.f, 0.f};
  f4 acc0 = zf, acc1 = zf;
  const int trow = t0 + w * 16 + c16;
  #pragma unroll
  for (int ks = 0; ks < 4; ks++) {
    bh8 a  = *(const bh8*)(xnB + ((size_t)(n * 16 + ks * 4 + q) * cHW + trow) * 8);
    bh8 b0 = *(const bh8*)(wqT + (size_t)(d0 + c16) * 128 + ks * 32 + q * 8);
    bh8 b1 = *(const bh8*)(wqT + (size_t)(d0 + 16 + c16) * 128 + ks * 32 + q * 8);
    acc0 = __builtin_amdgcn_mfma_f32_16x16x32_bf16(a, b0, acc0, 0, 0, 0);
    acc1 = __builtin_amdgcn_mfma_f32_16x16x32_bf16(a, b1, acc1, 0, 0, 0);
  }
  float blo = bq[d0 + c16], bhi = bq[d0 + 16 + c16];
  if (dg < 8) {
    float scl = (dg < 4) ? cQS : 1.0f;
    unsigned* dst = (dg < 4) ? qB : kB;
    #pragma unroll
    for (int r = 0; r < 4; r++) {
      unsigned pk = pack2bf((acc0[r] + blo) * scl, (acc1[r] + bhi) * scl);
      dst[((size_t)nh * cHW + t0 + w * 16 + q * 4 + r) * 16 + c16] = pk;
    }
  } else {
    #pragma unroll
    for (int r = 0; r < 4; r++) {
      vbuf[(w * 16 + q * 4 + r) * 36 + c16]      = acc0[r] + blo;
      vbuf[(w * 16 + q * 4 + r) * 36 + 16 + c16] = acc1[r] + bhi;
    }
    __syncthreads();
    // dword d in 32-key block: Q=d>>2, s=d&3;
    // keys (bk, bk+1) with bk = (s<2) ? 4Q+2s : 16+4Q+2(s-2)
    int d = threadIdx.x & 15, dh8 = (threadIdx.x >> 4) & 15;
    int Q = d >> 2, sd = d & 3;
    int bk = (sd < 2) ? (4 * Q + 2 * sd) : (16 + 4 * Q + 2 * (sd - 2));
    #pragma unroll
    for (int blk = 0; blk < 2; blk++)
      #pragma unroll
      for (int hh = 0; hh < 2; hh++) {
        int dh = dh8 + hh * 16;
        float lo = vbuf[(blk * 32 + bk) * 36 + dh];
        float hi = vbuf[(blk * 32 + bk + 1) * 36 + dh];
        vI[((size_t)nh * 32 + dh) * 2048 + (size_t)(t0 / 32 + blk) * 16 + d] = pack2bf(lo, hi);
      }
  }
}

// ---------------- flash half-tile: S^T -> prefetch next -> exp2/pack -> PV -
__device__ __forceinline__ void half_tile(
    const bh8* qfr, const bh8& kf0, const bh8& kf1, const bh8& vf0, const bh8& vf1,
    bh8& nkf0, bh8& nkf1, bh8& nvf0, bh8& nvf1,
    const unsigned short* kb, const unsigned short* vb, int ktn,
    f4 o[2][2], f4* lacc, int c16, int q, const bh8& ones) {
  const f4 zf = {0.f, 0.f, 0.f, 0.f};
  // S^T tiles [key-tile][q-tile]
  f4 st[2][2];
  st[0][0] = __builtin_amdgcn_mfma_f32_16x16x32_bf16(kf0, qfr[0], zf, 0, 0, 0);
  st[0][1] = __builtin_amdgcn_mfma_f32_16x16x32_bf16(kf0, qfr[1], zf, 0, 0, 0);
  st[1][0] = __builtin_amdgcn_mfma_f32_16x16x32_bf16(kf1, qfr[0], zf, 0, 0, 0);
  st[1][1] = __builtin_amdgcn_mfma_f32_16x16x32_bf16(kf1, qfr[1], zf, 0, 0, 0);
  // prefetch next half-tile's K/V (latency covered by exp2/pack/PV below)
  nkf0 = *(const bh8*)(kb + (size_t)(ktn + c16) * cDH + q * 8);
  nkf1 = *(const bh8*)(kb + (size_t)(ktn + 16 + c16) * cDH + q * 8);
  nvf0 = *(const bh8*)(vb + (size_t)c16 * cHW + ktn + q * 8);
  nvf1 = *(const bh8*)(vb + (size_t)(16 + c16) * cHW + ktn + q * 8);
  // exp2 (fixed max 0), in-register
  #pragma unroll
  for (int kt2 = 0; kt2 < 2; kt2++)
    #pragma unroll
    for (int qt2 = 0; qt2 < 2; qt2++)
      #pragma unroll
      for (int r = 0; r < 4; r++)
        st[kt2][qt2][r] = __builtin_amdgcn_exp2f(st[kt2][qt2][r]);
  // lane-local pack into P^T B-frags; PV + l on MFMA pipe
  #pragma unroll
  for (int qt2 = 0; qt2 < 2; qt2++) {
    u4 pu;
    pu.x = pack_trunc(st[0][qt2][0], st[0][qt2][1]);
    pu.y = pack_trunc(st[0][qt2][2], st[0][qt2][3]);
    pu.z = pack_trunc(st[1][qt2][0], st[1][qt2][1]);
    pu.w = pack_trunc(st[1][qt2][2], st[1][qt2][3]);
    bh8 pfr = __builtin_bit_cast(bh8, pu);
    o[0][qt2] = __builtin_amdgcn_mfma_f32_16x16x32_bf16(vf0, pfr, o[0][qt2], 0, 0, 0);
    o[1][qt2] = __builtin_amdgcn_mfma_f32_16x16x32_bf16(vf1, pfr, o[1][qt2], 0, 0, 0);
    lacc[qt2] = __builtin_amdgcn_mfma_f32_16x16x32_bf16(ones, pfr, lacc[qt2], 0, 0, 0);
  }
}

// ---------------- MFMA flash attention, operand-swapped, reg-prefetch -----
// Zero LDS; ping-pong K/V frag sets hide global-load latency.
// block = 256 (4 independent waves). grid (32 qb, 8 nh, SPLIT=8).
__global__ __launch_bounds__(256)
void flash_mfma(const unsigned short* __restrict__ qB,
                const unsigned short* __restrict__ kB,
                const unsigned short* __restrict__ vI,
                unsigned* __restrict__ opart, float* __restrict__ lpart) {
  const int w = threadIdx.x >> 6, L = threadIdx.x & 63;
  const int c16 = L & 15, q = L >> 4;
  const int qt = blockIdx.x * 4 + w, nh = blockIdx.y, ph = blockIdx.z;
  const f4 zf = {0.f, 0.f, 0.f, 0.f};
  const short oneb = 0x3F80;        // bf16 1.0
  const bh8 ones = {oneb, oneb, oneb, oneb, oneb, oneb, oneb, oneb};

  const unsigned short* qb = qB + ((size_t)nh * cHW + qt * 32) * cDH;
  bh8 qfr[2];
  qfr[0] = *(const bh8*)(qb + (size_t)c16 * cDH + q * 8);
  qfr[1] = *(const bh8*)(qb + (size_t)(16 + c16) * cDH + q * 8);

  f4 o[2][2] = {{zf, zf}, {zf, zf}};   // [dh-tile][q-tile], O^T C-layout
  f4 lacc[2] = {zf, zf};

  const unsigned short* kb = kB + (size_t)nh * cHW * cDH;
  const unsigned short* vb = vI + (size_t)nh * cDH * cHW;

  const int kbeg = ph * (cHW / SPLIT);
  const int kend = kbeg + cHW / SPLIT;

  // preload set A (keys kbeg..kbeg+31)
  bh8 kA0 = *(const bh8*)(kb + (size_t)(kbeg + c16) * cDH + q * 8);
  bh8 kA1 = *(const bh8*)(kb + (size_t)(kbeg + 16 + c16) * cDH + q * 8);
  bh8 vA0 = *(const bh8*)(vb + (size_t)c16 * cHW + kbeg + q * 8);
  bh8 vA1 = *(const bh8*)(vb + (size_t)(16 + c16) * cHW + kbeg + q * 8);
  bh8 kB0, kB1, vB0, vB1;

  for (int kt = kbeg; kt < kend; kt += 64) {
    half_tile(qfr, kA0, kA1, vA0, vA1, kB0, kB1, vB0, vB1,
              kb, vb, kt + 32, o, lacc, c16, q, ones);
    int ktn = (kt + 64 < kend) ? (kt + 64) : kbeg;  // wrap: harmless reload
    half_tile(qfr, kB0, kB1, vB0, vB1, kA0, kA1, vA0, vA1,
              kb, vb, ktn, o, lacc, c16, q, ones);
  }

  // epilogue: O^T[m=dh=q*4+r (+16)][n=q-row=c16]; uint4 store per q-tile
  size_t base_r = (size_t)ph * 32768 + (size_t)nh * cHW + (size_t)qt * 32;
  #pragma unroll
  for (int qt2 = 0; qt2 < 2; qt2++) {
    size_t rr = base_r + qt2 * 16 + c16;
    if (q == 0) lpart[rr] = lacc[qt2][0];   // all rows identical (ones-A)
    u4 pk;
    pk.x = pack_trunc(o[0][qt2][0], o[1][qt2][0]);
    pk.y = pack_trunc(o[0][qt2][1], o[1][qt2][1]);
    pk.z = pack_trunc(o[0][qt2][2], o[1][qt2][2]);
    pk.w = pack_trunc(o[0][qt2][3], o[1][qt2][3]);
    *(u4*)(opart + rr * 16 + q * 4) = pk;
  }
}

// ---------------- split-K combine -> yB bf16 [row][32] --------------------
// grid 128, block 256; one thread per row
__global__ __launch_bounds__(256)
void combine(const unsigned* __restrict__ opart, const float* __restrict__ lpart,
             unsigned* __restrict__ yB) {
  size_t r = (size_t)blockIdx.x * 256 + threadIdx.x;
  float l = 0.f;
  #pragma unroll
  for (int p = 0; p < SPLIT; p++) l += lpart[(size_t)p * 32768 + r];
  float e[32];
  #pragma unroll
  for (int j = 0; j < 32; j++) e[j] = 0.f;
  #pragma unroll
  for (int p = 0; p < SPLIT; p++) {
    const uint4* op = (const uint4*)(opart + ((size_t)p * 32768 + r) * 16);
    #pragma unroll
    for (int j = 0; j < 4; j++) {
      uint4 v = op[j];
      e[j*4+0] += bflo(v.x); e[16+j*4+0] += bfhi(v.x);
      e[j*4+1] += bflo(v.y); e[16+j*4+1] += bfhi(v.y);
      e[j*4+2] += bflo(v.z); e[16+j*4+2] += bfhi(v.z);
      e[j*4+3] += bflo(v.w); e[16+j*4+3] += bfhi(v.w);
    }
  }
  float inv = 1.0f / l;
  unsigned pk[16];
  #pragma unroll
  for (int m = 0; m < 16; m++) pk[m] = pack2bf(e[2*m] * inv, e[2*m+1] * inv);
  uint4* dst = (uint4*)(yB + r * 16);
  #pragma unroll
  for (int j = 0; j < 4; j++)
    dst[j] = make_uint4(pk[4*j], pk[4*j+1], pk[4*j+2], pk[4*j+3]);
}

// ---------------- out projection (MFMA) + per-block GN2 partials ----------
// grid (64 tt, 4 dg, 2 n), block 256. Stats via LDS/shfl reduce to
// part2[blk][8] — one plain store per value, NO atomics (R6 lesson).
__global__ __launch_bounds__(256)
void out_mfma(const unsigned short* __restrict__ yB, const unsigned short* __restrict__ woT,
              const float* __restrict__ bo, float* __restrict__ proj,
              float* __restrict__ part2) {
  __shared__ float obuf[64 * 36];
  __shared__ float sred[4][16][4];
  const int L = threadIdx.x & 63, w = threadIdx.x >> 6;
  const int c16 = L & 15, q = L >> 4;
  const int t0 = blockIdx.x * 64, d0 = blockIdx.y * 32, n = blockIdx.z;
  const f4 zf = {0.f, 0.f, 0.f, 0.f};
  f4 acc0 = zf, acc1 = zf;
  const int trow = t0 + w * 16 + c16;
  #pragma unroll
  for (int h = 0; h < 4; h++) {
    bh8 a  = *(const bh8*)(yB + ((size_t)(n * 4 + h) * cHW + trow) * 32 + q * 8);
    bh8 b0 = *(const bh8*)(woT + (size_t)(d0 + c16) * 128 + h * 32 + q * 8);
    bh8 b1 = *(const bh8*)(woT + (size_t)(d0 + 16 + c16) * 128 + h * 32 + q * 8);
    acc0 = __builtin_amdgcn_mfma_f32_16x16x32_bf16(a, b0, acc0, 0, 0, 0);
    acc1 = __builtin_amdgcn_mfma_f32_16x16x32_bf16(a, b1, acc1, 0, 0, 0);
  }
  float blo = bo[d0 + c16], bhi = bo[d0 + 16 + c16];
  float v0[4], v1[4];
  float sa = 0.f, sa2 = 0.f, sb = 0.f, sb2 = 0.f;
  #pragma unroll
  for (int r = 0; r < 4; r++) {
    v0[r] = acc0[r] + blo; v1[r] = acc1[r] + bhi;
    sa += v0[r]; sa2 += v0[r]*v0[r];
    sb += v1[r]; sb2 += v1[r]*v1[r];
  }
  // reduce over q (t within wave): xor 16, 32
  #pragma unroll
  for (int d = 16; d < 64; d <<= 1) {
    sa += __shfl_xor(sa, d, 64);  sa2 += __shfl_xor(sa2, d, 64);
    sb += __shfl_xor(sb, d, 64);  sb2 += __shfl_xor(sb2, d, 64);
  }
  if (q == 0) {
    sred[w][c16][0] = sa; sred[w][c16][1] = sa2;
    sred[w][c16][2] = sb; sred[w][c16][3] = sb2;
  }
  #pragma unroll
  for (int r = 0; r < 4; r++) {
    obuf[(w * 16 + q * 4 + r) * 36 + c16]      = v0[r];
    obuf[(w * 16 + q * 4 + r) * 36 + 16 + c16] = v1[r];
  }
  __syncthreads();
  // per-block group partials: groups d0/8 + gi, gi=0..3
  if (threadIdx.x < 8) {
    int gi = threadIdx.x >> 1, vi = threadIdx.x & 1;
    float v = 0.f;
    #pragma unroll
    for (int ww = 0; ww < 4; ww++)
      #pragma unroll
      for (int k = 0; k < 8; k++)
        v += sred[ww][(gi & 1) * 8 + k][(gi >> 1) * 2 + vi];
    int blk = blockIdx.x + 64 * (blockIdx.y + 4 * blockIdx.z);
    part2[blk * 8 + gi * 2 + vi] = v;
  }
  int t16 = threadIdx.x & 15, d8 = (threadIdx.x >> 4) & 15;
  #pragma unroll
  for (int tc = 0; tc < 4; tc++)
    #pragma unroll
    for (int hh = 0; hh < 2; hh++) {
      int d = d8 + hh * 16;
      proj[((size_t)n * cC + d0 + d) * cHW + t0 + tc * 16 + t16] =
          obuf[(tc * 16 + t16) * 36 + d];
    }
}

// ---------------- GN2 apply + residual (stats from part2 partials) --------
// grid 256 (one channel per block), block 256
__global__ __launch_bounds__(256)
void gn2_apply(const float* __restrict__ x, const float* __restrict__ proj,
               const float* __restrict__ p1, const float* __restrict__ part2,
               const float* __restrict__ s1, const float* __restrict__ o1,
               const float* __restrict__ s2, const float* __restrict__ o2,
               float* __restrict__ out) {
  int tid = blockIdx.x * 256 + threadIdx.x;
  int Cg = blockIdx.x;
  int n = Cg >> 7, ch = Cg & 127, g = ch >> 3, ng = n * 16 + g;
  float sa = 0.f, sb = 0.f;
  #pragma unroll
  for (int p = 0; p < 8; p++) { sa += p1[(ng*8+p)*2]; sb += p1[(ng*8+p)*2+1]; }
  // GN2 stats: wave-reduce 64 per-tile partials (all waves redundantly)
  int dg = g >> 2, gi = g & 3;
  int lane = threadIdx.x & 63;
  int pbase = (lane + 64 * (dg + 4 * n)) * 8 + gi * 2;
  float ta = part2[pbase], tb = part2[pbase + 1];
  #pragma unroll
  for (int d = 1; d < 64; d <<= 1) {
    ta += __shfl_xor(ta, d, 64);
    tb += __shfl_xor(tb, d, 64);
  }
  float mu1 = sa * (1.0f/32768.0f);
  float ri1 = rsqrtf(sb * (1.0f/32768.0f) - mu1*mu1 + cEPS);
  float a1 = ri1 * s1[ch], b1 = o1[ch] - mu1 * a1;
  float mu2 = ta * (1.0f/32768.0f);
  float ri2 = rsqrtf(tb * (1.0f/32768.0f) - mu2*mu2 + cEPS);
  float a2 = ri2 * s2[ch], b2 = o2[ch] - mu2 * a2;
  const float4* x4 = (const float4*)x;
  const float4* pr4 = (const float4*)proj;
  float4* o4 = (float4*)out;
  #pragma unroll
  for (int i = 0; i < 4; i++) {
    size_t f = (size_t)tid * 4 + i;
    float4 xv = x4[f], pv = pr4[f];
    float4 r;
    r.x = xv.x * a1 + b1 + pv.x * a2 + b2;
    r.y = xv.y * a1 + b1 + pv.y * a2 + b2;
    r.z = xv.z * a1 + b1 + pv.z * a2 + b2;
    r.w = xv.w * a1 + b1 + pv.w * a2 + b2;
    o4[f] = r;
  }
}

// ---------------- launcher ------------------------------------------------
// Workspace: ~25.1 MB via lifetime aliasing (region B holds xnB+wqT early
// [dead after qkv], opart mid [dead after combine], proj late).
extern "C" void kernel_launch(void* const* d_in, const int* in_sizes, int n_in,
                              void* d_out, int out_size, void* d_ws, size_t ws_size,
                              hipStream_t stream) {
  const float* x     = (const float*)d_in[0];
  const float* w_qkv = (const float*)d_in[1];
  const float* b_qkv = (const float*)d_in[2];
  const float* w_out = (const float*)d_in[3];
  const float* b_out = (const float*)d_in[4];
  const float* g1s   = (const float*)d_in[5];
  const float* g1o   = (const float*)d_in[6];
  const float* g2s   = (const float*)d_in[7];
  const float* g2o   = (const float*)d_in[8];
  float* out = (float*)d_out;

  // ---- Region A (persistent within launch) ----
  unsigned* qB = (unsigned*)d_ws;                         // 2 MB
  unsigned* kB = qB + 524288;                             // 2 MB
  unsigned* vI = kB + 524288;                             // 2 MB
  unsigned* yB = vI + 524288;                             // 2 MB
  unsigned short* woT = (unsigned short*)(yB + 524288);   // 32 KB
  float* stats1 = (float*)(woT + 16384);                  // 512 fl
  float* part2  = stats1 + 512;                           // 4096 fl (16 KB)
  float* lpart  = part2 + 4096;                           // SPLIT*32768 fl (1 MB)
  // ---- Region B (16 MB, time-multiplexed) ----
  unsigned* opart = (unsigned*)(lpart + (size_t)SPLIT * 32768);  // 16 MB
  float* proj = (float*)opart;                            // alias (first 4 MB)
  unsigned short* xnB = (unsigned short*)opart;           // alias (first 2 MB)
  unsigned short* wqT = xnB + 1048576;                    // alias (next 96 KB)

  prep      <<<dim3(272),           256, 0, stream>>>(x, stats1, w_qkv, w_out, wqT, woT);
  gn1_pack  <<<dim3(16, 16, 2),     256, 0, stream>>>(x, stats1, g1s, g1o, xnB);
  qkv_mfma  <<<dim3(64, 12, 2),     256, 0, stream>>>(xnB, wqT, b_qkv, qB, kB, vI);
  flash_mfma<<<dim3(32, 8, SPLIT),  256, 0, stream>>>((const unsigned short*)qB,
                                                      (const unsigned short*)kB,
                                                      (const unsigned short*)vI,
                                                      opart, lpart);
  combine   <<<dim3(128),           256, 0, stream>>>(opart, lpart, yB);
  out_mfma  <<<dim3(64, 4, 2),      256, 0, stream>>>((const unsigned short*)yB, woT,
                                                      b_out, proj, part2);
  gn2_apply <<<dim3(256),           256, 0, stream>>>(x, proj, stats1, part2,
                                                      g1s, g1o, g2s, g2o, out);
}